// Round 3
// baseline (147.976 us; speedup 1.0000x reference)
//
#include <hip/hip_runtime.h>

typedef short  bf16x8 __attribute__((ext_vector_type(8)));
typedef float  f32x16 __attribute__((ext_vector_type(16)));

__device__ __forceinline__ unsigned short f2bf(float x) {
    unsigned u = __builtin_bit_cast(unsigned, x);
    u += 0x7FFF + ((u >> 16) & 1);          // RNE
    return (unsigned short)(u >> 16);
}
__device__ __forceinline__ float bf2f(unsigned short h) {
    unsigned u = ((unsigned)h) << 16;
    return __builtin_bit_cast(float, u);
}

// Pack padding points into MFMA-A-operand planes in ws.
// Row j (16 bf16, K=16):
//   k0-2:  qxh,qyh,qzh      (pairs B: pxh,pyh,pzh)   hi*hi
//   k3-5:  qxl,qyl,qzl      (pairs B: pxh,pyh,pzh)   lo*hi
//   k6-8:  qxh,qyh,qzh      (pairs B: pxl,pyl,pzl)   hi*lo
//   k9-11: qxl,qyl,qzl      (pairs B: pxl,pyl,pzl)   lo*lo
//   k12-13: nch,ncl         (pairs B: 1,1)           negc bias, split
//   k14-15: 0
// plane0 = k0-7 (16B/row), plane1 = k8-15 (16B/row) — matches A-frag lane split:
// lanes 0-31 hold k0-7 of row m=lane&31, lanes 32-63 hold k8-15.
__global__ __launch_bounds__(256) void dens_pack_kernel(
    const float* __restrict__ pad, uint4* __restrict__ ws, int M, int mpad)
{
    const int j = blockIdx.x * 256 + threadIdx.x;
    if (j >= mpad) return;

    float qx = 0.f, qy = 0.f, qz = 0.f;
    float negc = -1.0e6f;                       // padded rows: never within radius
    if (j < M) {
        qx = pad[3 * j]; qy = pad[3 * j + 1]; qz = pad[3 * j + 2];
        negc = 0.125f - 0.5f * (qx * qx + qy * qy + qz * qz);   // (r^2 - |q|^2)/2
    }
    const unsigned short xh = f2bf(qx), yh = f2bf(qy), zh = f2bf(qz);
    const unsigned short xl = f2bf(qx - bf2f(xh));
    const unsigned short yl = f2bf(qy - bf2f(yh));
    const unsigned short zl = f2bf(qz - bf2f(zh));
    const unsigned short ch = f2bf(negc);
    const unsigned short cl = f2bf(negc - bf2f(ch));

    uint4 p0, p1;
    p0.x = (unsigned)xh | ((unsigned)yh << 16);   // k0,k1
    p0.y = (unsigned)zh | ((unsigned)xl << 16);   // k2,k3
    p0.z = (unsigned)yl | ((unsigned)zl << 16);   // k4,k5
    p0.w = (unsigned)xh | ((unsigned)yh << 16);   // k6,k7
    p1.x = (unsigned)zh | ((unsigned)xl << 16);   // k8,k9
    p1.y = (unsigned)yl | ((unsigned)zl << 16);   // k10,k11
    p1.z = (unsigned)ch | ((unsigned)cl << 16);   // k12,k13
    p1.w = 0;                                     // k14,k15
    ws[j]        = p0;                            // plane0
    ws[mpad + j] = p1;                            // plane1
}

// One block per 32-point i-tile; 4 waves split the j-tiles (stride 4).
// Per j-tile: one global dwordx4 (A-frag from packed ws, L2-hit), one
// v_mfma_f32_32x32x16_bf16, 16x (v_cmp_ge + addc). No LDS staging, no atomics.
__global__ __launch_bounds__(256) void dens_mfma_kernel(
    const float* __restrict__ pc,     // [N,3] pointcloud
    const char*  __restrict__ wsA,    // packed A planes
    int* __restrict__ out,            // [N] counts
    int N, int jt, int p1off)         // jt = #j-tiles, p1off = plane1 byte offset
{
    const int lane = threadIdx.x & 63;
    const int w    = threadIdx.x >> 6;   // wave id 0..3
    const int n    = lane & 31;          // output col within tile = i index
    const int half = lane >> 5;          // k-chunk: 0 -> k0-7, 1 -> k8-15

    // ---- B-frag (i-operand), fixed for the whole kernel ----
    const int i = blockIdx.x * 32 + n;
    float px = 0.f, py = 0.f, pz = 0.f, ha = 3.0e38f;
    if (i < N) {
        px = pc[3 * i]; py = pc[3 * i + 1]; pz = pc[3 * i + 2];
        ha = 0.5f * (px * px + py * py + pz * pz);   // |p|^2 / 2, full f32
    }
    const short xh = (short)f2bf(px), yh = (short)f2bf(py), zh = (short)f2bf(pz);
    const short xl = (short)f2bf(px - bf2f((unsigned short)xh));
    const short yl = (short)f2bf(py - bf2f((unsigned short)yh));
    const short zl = (short)f2bf(pz - bf2f((unsigned short)zh));
    const short ONE = (short)0x3F80;     // bf16 1.0

    const bf16x8 B0 = {xh, yh, zh, xh, yh, zh, xl, yl};   // k0-7
    const bf16x8 B1 = {zl, xl, yl, zl, ONE, ONE, 0, 0};   // k8-15
    const bf16x8 B  = half ? B1 : B0;

    // ---- A-frag addressing: lane-fixed byte offset, +512B per j-tile ----
    const char* abase = wsA + (half ? p1off : 0) + n * 16;

    const f32x16 Z = {0.f};   // zero accumulator, hoisted
    int cnt = 0;

    auto loadA = [&](int t) -> bf16x8 {
        return *(const bf16x8*)(abase + (size_t)t * 512);
    };

    int tmax = jt - 1;
    bf16x8 A0 = loadA(min(w, tmax));
    bf16x8 A1 = loadA(min(w + 4, tmax));

    #pragma unroll 2
    for (int t = w; t < jt; t += 4) {
        bf16x8 An = loadA(min(t + 8, tmax));          // prefetch depth 2
        f32x16 s = __builtin_amdgcn_mfma_f32_32x32x16_bf16(A0, B, Z, 0, 0, 0);
        A0 = A1; A1 = An;
        #pragma unroll
        for (int r = 0; r < 16; ++r)
            cnt += (s[r] >= ha);                      // v_cmp_ge_f32 + addc
    }

    // ---- reduce: col n lives in lanes n and n+32; then across 4 waves ----
    int tot = cnt + __shfl_xor(cnt, 32);
    __shared__ int red[4][32];
    if (lane < 32) red[w][n] = tot;
    __syncthreads();
    if (threadIdx.x < 32) {
        const int ii = blockIdx.x * 32 + threadIdx.x;
        if (ii < N)
            out[ii] = red[0][threadIdx.x] + red[1][threadIdx.x] +
                      red[2][threadIdx.x] + red[3][threadIdx.x];
    }
}

extern "C" void kernel_launch(void* const* d_in, const int* in_sizes, int n_in,
                              void* d_out, int out_size, void* d_ws, size_t ws_size,
                              hipStream_t stream) {
    const float* pc  = (const float*)d_in[0];   // [N,3] pointcloud
    const float* pad = (const float*)d_in[1];   // [M,3] pointcloud_padding
    int* out = (int*)d_out;

    const int N = in_sizes[0] / 3;              // 20000
    const int M = in_sizes[1] / 3;              // 25000
    const int jt   = (M + 31) / 32;             // 782 j-tiles
    const int mpad = jt * 32;                   // padded rows (25024)
    // ws usage: mpad*32 bytes (~800 KB)

    dens_pack_kernel<<<(mpad + 255) / 256, 256, 0, stream>>>(
        pad, (uint4*)d_ws, M, mpad);

    dens_mfma_kernel<<<(N + 31) / 32, 256, 0, stream>>>(
        pc, (const char*)d_ws, out, N, jt, mpad * 16);
}

// Round 4
// 95.586 us; speedup vs baseline: 1.5481x; 1.5481x over previous
//
#include <hip/hip_runtime.h>

typedef short  bf16x8 __attribute__((ext_vector_type(8)));
typedef float  f32x16 __attribute__((ext_vector_type(16)));

__device__ __forceinline__ unsigned short f2bf(float x) {
    unsigned u = __builtin_bit_cast(unsigned, x);
    u += 0x7FFF + ((u >> 16) & 1);          // RNE
    return (unsigned short)(u >> 16);
}
__device__ __forceinline__ float bf2f(unsigned short h) {
    unsigned u = ((unsigned)h) << 16;
    return __builtin_bit_cast(float, u);
}

// ---- pack padding points into MFMA-A planes + zero the output ----
// Row j (K=16 bf16): k0-2 qh | k3-5 ql | k6-8 qh | k9-11 ql | k12-13 negc h/l | 0,0
// plane0 = k0-7 (lanes 0-31), plane1 = k8-15 (lanes 32-63).
__global__ __launch_bounds__(256) void dens_pack_kernel(
    const float* __restrict__ pad, uint4* __restrict__ ws,
    int* __restrict__ out, int M, int mpad, int N)
{
    const int j = blockIdx.x * 256 + threadIdx.x;
    if (j < N) out[j] = 0;                      // fold output zeroing here
    if (j >= mpad) return;

    float qx = 0.f, qy = 0.f, qz = 0.f;
    float negc = -1.0e6f;                       // padded rows never match
    if (j < M) {
        qx = pad[3 * j]; qy = pad[3 * j + 1]; qz = pad[3 * j + 2];
        negc = 0.125f - 0.5f * (qx * qx + qy * qy + qz * qz);   // (r^2 - |q|^2)/2
    }
    const unsigned short xh = f2bf(qx), yh = f2bf(qy), zh = f2bf(qz);
    const unsigned short xl = f2bf(qx - bf2f(xh));
    const unsigned short yl = f2bf(qy - bf2f(yh));
    const unsigned short zl = f2bf(qz - bf2f(zh));
    const unsigned short ch = f2bf(negc);
    const unsigned short cl = f2bf(negc - bf2f(ch));

    uint4 p0, p1;
    p0.x = (unsigned)xh | ((unsigned)yh << 16);   // k0,k1
    p0.y = (unsigned)zh | ((unsigned)xl << 16);   // k2,k3
    p0.z = (unsigned)yl | ((unsigned)zl << 16);   // k4,k5
    p0.w = (unsigned)xh | ((unsigned)yh << 16);   // k6,k7
    p1.x = (unsigned)zh | ((unsigned)xl << 16);   // k8,k9
    p1.y = (unsigned)yl | ((unsigned)zl << 16);   // k10,k11
    p1.z = (unsigned)ch | ((unsigned)cl << 16);   // k12,k13
    p1.w = 0;                                     // k14,k15
    ws[j]        = p0;                            // plane0
    ws[mpad + j] = p1;                            // plane1
}

__device__ __forceinline__ void make_bfrag(const float* __restrict__ pc,
                                           int i, int N, int half,
                                           bf16x8& B, float& ha)
{
    float px = 0.f, py = 0.f, pz = 0.f;
    ha = 3.0e38f;
    if (i < N) {
        px = pc[3 * i]; py = pc[3 * i + 1]; pz = pc[3 * i + 2];
        ha = 0.5f * (px * px + py * py + pz * pz);   // |p|^2/2, fp32
    }
    const short xh = (short)f2bf(px), yh = (short)f2bf(py), zh = (short)f2bf(pz);
    const short xl = (short)f2bf(px - bf2f((unsigned short)xh));
    const short yl = (short)f2bf(py - bf2f((unsigned short)yh));
    const short zl = (short)f2bf(pz - bf2f((unsigned short)zh));
    const short ONE = (short)0x3F80;
    const bf16x8 B0 = {xh, yh, zh, xh, yh, zh, xl, yl};   // k0-7
    const bf16x8 B1 = {zl, xl, yl, zl, ONE, ONE, 0, 0};   // k8-15
    B = half ? B1 : B0;
}

// grid (313 i-tiles x JS j-splits), 256 thr = 4 waves.
// Each block: 64-wide i-tile; each wave-stream (16 total) strides j-tiles by 16.
// Per j-tile: 1 global dwordx4 (A-frag, L2-hit) feeding 2 MFMAs (i0, i0+32).
#define JS 4
__global__ __launch_bounds__(256, 2) void dens_mfma_kernel(
    const float* __restrict__ pc,     // [N,3] pointcloud
    const char*  __restrict__ wsA,    // packed A planes
    int* __restrict__ out,            // [N] counts (pre-zeroed)
    int N, int jt, int p1off)
{
    const int lane = threadIdx.x & 63;
    const int w    = threadIdx.x >> 6;   // wave 0..3
    const int n    = lane & 31;          // output col within 32-tile = i
    const int half = lane >> 5;          // k-chunk 0/1

    const int ibase = blockIdx.x * 64;
    bf16x8 B0, B1; float ha0, ha1;
    make_bfrag(pc, ibase + n,      N, half, B0, ha0);
    make_bfrag(pc, ibase + 32 + n, N, half, B1, ha1);

    const char* abase = wsA + (half ? p1off : 0) + n * 16;
    const int stream = blockIdx.y * 4 + w;          // 0..15, stride 16
    const int tmax = jt - 1;

    const f32x16 Z = {0.f};                         // loop-invariant zero C
    int c0 = 0, c1 = 0;

    bf16x8 A0 = *(const bf16x8*)(abase + (size_t)stream * 512);
    bf16x8 A1 = *(const bf16x8*)(abase + (size_t)min(stream + 16, tmax) * 512);

    for (int t = stream; t < jt; t += 16) {
        bf16x8 An = *(const bf16x8*)(abase + (size_t)min(t + 32, tmax) * 512);
        f32x16 s0 = __builtin_amdgcn_mfma_f32_32x32x16_bf16(A0, B0, Z, 0, 0, 0);
        #pragma unroll
        for (int r = 0; r < 16; ++r) c0 += (s0[r] >= ha0);
        f32x16 s1 = __builtin_amdgcn_mfma_f32_32x32x16_bf16(A0, B1, Z, 0, 0, 0);
        #pragma unroll
        for (int r = 0; r < 16; ++r) c1 += (s1[r] >= ha1);
        A0 = A1; A1 = An;
    }

    // col n lives in lanes n and n+32 (complementary row halves)
    int t0 = c0 + __shfl_xor(c0, 32);
    int t1 = c1 + __shfl_xor(c1, 32);

    __shared__ int red[4][64];
    if (lane < 32) { red[w][n] = t0; red[w][n + 32] = t1; }
    __syncthreads();
    if (threadIdx.x < 64) {
        const int ii = ibase + threadIdx.x;
        if (ii < N) {
            const int s = red[0][threadIdx.x] + red[1][threadIdx.x] +
                          red[2][threadIdx.x] + red[3][threadIdx.x];
            atomicAdd(&out[ii], s);
        }
    }
}

extern "C" void kernel_launch(void* const* d_in, const int* in_sizes, int n_in,
                              void* d_out, int out_size, void* d_ws, size_t ws_size,
                              hipStream_t stream) {
    const float* pc  = (const float*)d_in[0];   // [N,3] pointcloud
    const float* pad = (const float*)d_in[1];   // [M,3] pointcloud_padding
    int* out = (int*)d_out;

    const int N = in_sizes[0] / 3;              // 20000
    const int M = in_sizes[1] / 3;              // 25000
    const int jt   = (M + 31) / 32;             // 782 j-tiles
    const int mpad = jt * 32;                   // 25024 padded rows (~800 KB ws)

    dens_pack_kernel<<<(mpad + 255) / 256, 256, 0, stream>>>(
        pad, (uint4*)d_ws, out, M, mpad, N);

    dim3 grid((N + 63) / 64, JS);               // 313 x 4
    dens_mfma_kernel<<<grid, 256, 0, stream>>>(
        pc, (const char*)d_ws, out, N, jt, mpad * 16);
}

// Round 6
// 93.165 us; speedup vs baseline: 1.5883x; 1.0260x over previous
//
#include <hip/hip_runtime.h>

typedef short  bf16x8 __attribute__((ext_vector_type(8)));
typedef float  f32x16 __attribute__((ext_vector_type(16)));

#define JS      8            // j-splits (grid.y)
#define STREAMS (JS * 4)     // wave-streams per i-tile (stride in j-tiles)
#define JTPAD   STREAMS      // extra packed j-tiles => branchless prefetch

__device__ __forceinline__ unsigned short f2bf(float x) {
    unsigned u = __builtin_bit_cast(unsigned, x);
    u += 0x7FFF + ((u >> 16) & 1);          // RNE
    return (unsigned short)(u >> 16);
}
__device__ __forceinline__ float bf2f(unsigned short h) {
    unsigned u = ((unsigned)h) << 16;
    return __builtin_bit_cast(float, u);
}

// ---- pack padding points into MFMA-A planes + zero the output ----
// Row j (K=16 bf16): k0-2 qh | k3-5 ql | k6-8 qh | k9-11 ql | k12-13 negc h/l | 0,0
// plane0 = k0-7 (lanes 0-31), plane1 = k8-15 (lanes 32-63).
__global__ __launch_bounds__(256) void dens_pack_kernel(
    const float* __restrict__ pad, uint4* __restrict__ ws,
    int* __restrict__ out, int M, int mtot, int N)
{
    const int j = blockIdx.x * 256 + threadIdx.x;
    if (j < N) out[j] = 0;                      // fold output zeroing here
    if (j >= mtot) return;

    float qx = 0.f, qy = 0.f, qz = 0.f;
    float negc = -1.0e6f;                       // padded rows never match
    if (j < M) {
        qx = pad[3 * j]; qy = pad[3 * j + 1]; qz = pad[3 * j + 2];
        negc = 0.125f - 0.5f * (qx * qx + qy * qy + qz * qz);   // (r^2 - |q|^2)/2
    }
    const unsigned short xh = f2bf(qx), yh = f2bf(qy), zh = f2bf(qz);
    const unsigned short xl = f2bf(qx - bf2f(xh));
    const unsigned short yl = f2bf(qy - bf2f(yh));
    const unsigned short zl = f2bf(qz - bf2f(zh));
    const unsigned short ch = f2bf(negc);
    const unsigned short cl = f2bf(negc - bf2f(ch));

    uint4 p0, p1;
    p0.x = (unsigned)xh | ((unsigned)yh << 16);   // k0,k1
    p0.y = (unsigned)zh | ((unsigned)xl << 16);   // k2,k3
    p0.z = (unsigned)yl | ((unsigned)zl << 16);   // k4,k5
    p0.w = (unsigned)xh | ((unsigned)yh << 16);   // k6,k7
    p1.x = (unsigned)zh | ((unsigned)xl << 16);   // k8,k9
    p1.y = (unsigned)yl | ((unsigned)zl << 16);   // k10,k11
    p1.z = (unsigned)ch | ((unsigned)cl << 16);   // k12,k13
    p1.w = 0;                                     // k14,k15
    ws[j]        = p0;                            // plane0
    ws[mtot + j] = p1;                            // plane1
}

__device__ __forceinline__ void make_bfrag(const float* __restrict__ pc,
                                           int i, int N, int half,
                                           bf16x8& B, float& ha)
{
    float px = 0.f, py = 0.f, pz = 0.f;
    ha = 3.0e38f;                                // i-pad: s >= 3e38 never true
    if (i < N) {
        px = pc[3 * i]; py = pc[3 * i + 1]; pz = pc[3 * i + 2];
        ha = 0.5f * (px * px + py * py + pz * pz);   // |p|^2/2, fp32
    }
    const short xh = (short)f2bf(px), yh = (short)f2bf(py), zh = (short)f2bf(pz);
    const short xl = (short)f2bf(px - bf2f((unsigned short)xh));
    const short yl = (short)f2bf(py - bf2f((unsigned short)yh));
    const short zl = (short)f2bf(pz - bf2f((unsigned short)zh));
    const short ONE = (short)0x3F80;
    const bf16x8 B0 = {xh, yh, zh, xh, yh, zh, xl, yl};   // k0-7
    const bf16x8 B1 = {zl, xl, yl, zl, ONE, ONE, 0, 0};   // k8-15
    B = half ? B1 : B0;
}

// grid (313 x JS), 256 thr. 64-wide i-tile; STREAMS wave-streams stride j-tiles.
// Per j-tile: 1 dwordx4 A-load (L2-hit) -> 2 MFMAs (C=0, R3-proven numerics),
// then s[r] >= ha compare-count. Branchless depth-1 prefetch into JTPAD tiles.
__global__ __launch_bounds__(256, 2) void dens_mfma_kernel(
    const float* __restrict__ pc,     // [N,3] pointcloud
    const char*  __restrict__ wsA,    // packed A planes (jt+JTPAD tiles)
    int* __restrict__ out,            // [N] counts (pre-zeroed)
    int N, int jt, int p1off)
{
    const int lane = threadIdx.x & 63;
    const int w    = threadIdx.x >> 6;   // wave 0..3
    const int n    = lane & 31;          // output col within 32-tile = i
    const int half = lane >> 5;          // k-chunk 0/1

    const int ibase = blockIdx.x * 64;
    bf16x8 B0, B1; float ha0, ha1;
    make_bfrag(pc, ibase + n,      N, half, B0, ha0);
    make_bfrag(pc, ibase + 32 + n, N, half, B1, ha1);

    const int stream = blockIdx.y * 4 + w;          // 0..STREAMS-1
    const char* aptr = wsA + (half ? p1off : 0) + n * 16 + (size_t)stream * 512;

    const f32x16 Z = {0.f};                         // zero accumulator (R3-proven)
    int c0 = 0, c1 = 0;

    bf16x8 A = *(const bf16x8*)aptr;                // tile `stream`

    for (int t = stream; t < jt; t += STREAMS) {
        const bf16x8 An = *(const bf16x8*)(aptr + STREAMS * 512);  // next tile (pad-safe)
        const f32x16 s0 = __builtin_amdgcn_mfma_f32_32x32x16_bf16(A, B0, Z, 0, 0, 0);
        const f32x16 s1 = __builtin_amdgcn_mfma_f32_32x32x16_bf16(A, B1, Z, 0, 0, 0);
        #pragma unroll
        for (int r = 0; r < 16; ++r) c0 += (s0[r] >= ha0);
        #pragma unroll
        for (int r = 0; r < 16; ++r) c1 += (s1[r] >= ha1);
        A = An;
        aptr += STREAMS * 512;
    }

    // col n lives in lanes n and n+32 (complementary row halves)
    int g0 = c0 + __shfl_xor(c0, 32);
    int g1 = c1 + __shfl_xor(c1, 32);

    __shared__ int red[4][64];
    if (lane < 32) { red[w][n] = g0; red[w][n + 32] = g1; }
    __syncthreads();
    if (threadIdx.x < 64) {
        const int ii = ibase + threadIdx.x;
        if (ii < N) {
            const int s = red[0][threadIdx.x] + red[1][threadIdx.x] +
                          red[2][threadIdx.x] + red[3][threadIdx.x];
            atomicAdd(&out[ii], s);
        }
    }
}

extern "C" void kernel_launch(void* const* d_in, const int* in_sizes, int n_in,
                              void* d_out, int out_size, void* d_ws, size_t ws_size,
                              hipStream_t stream) {
    const float* pc  = (const float*)d_in[0];   // [N,3] pointcloud
    const float* pad = (const float*)d_in[1];   // [M,3] pointcloud_padding
    int* out = (int*)d_out;

    const int N = in_sizes[0] / 3;              // 20000
    const int M = in_sizes[1] / 3;              // 25000
    const int jt   = (M + 31) / 32;             // 782 j-tiles
    const int jtp  = jt + JTPAD;                // + pad tiles for prefetch
    const int mtot = jtp * 32;                  // packed rows (~833 KB in ws)

    dens_pack_kernel<<<(mtot + 255) / 256, 256, 0, stream>>>(
        pad, (uint4*)d_ws, out, M, mtot, N);

    dim3 grid((N + 63) / 64, JS);               // 313 x 8
    dens_mfma_kernel<<<grid, 256, 0, stream>>>(
        pc, (const char*)d_ws, out, N, jt, mtot * 16);
}

// Round 7
// 92.934 us; speedup vs baseline: 1.5923x; 1.0025x over previous
//
#include <hip/hip_runtime.h>

typedef short  bf16x8 __attribute__((ext_vector_type(8)));
typedef float  f32x16 __attribute__((ext_vector_type(16)));

#define JS      8            // j-splits (grid.y)
#define STREAMS (JS * 4)     // wave-streams per i-tile (stride in j-tiles)
#define JTPAD   STREAMS      // extra packed j-tiles => branchless prefetch

__device__ __forceinline__ unsigned short f2bf(float x) {
    unsigned u = __builtin_bit_cast(unsigned, x);
    u += 0x7FFF + ((u >> 16) & 1);          // RNE
    return (unsigned short)(u >> 16);
}
__device__ __forceinline__ float bf2f(unsigned short h) {
    unsigned u = ((unsigned)h) << 16;
    return __builtin_bit_cast(float, u);
}

// ---- pack padding points into MFMA-A planes + zero the output ----
// Row j (K=16 bf16): k0-2 qh | k3-5 ql | k6-8 qh | k9-11 ql | k12-13 negc h/l | 0,0
// plane0 = k0-7 (lanes 0-31), plane1 = k8-15 (lanes 32-63).
__global__ __launch_bounds__(256) void dens_pack_kernel(
    const float* __restrict__ pad, uint4* __restrict__ ws,
    int* __restrict__ out, int M, int mtot, int N)
{
    const int j = blockIdx.x * 256 + threadIdx.x;
    if (j < N) out[j] = 0;                      // fold output zeroing here
    if (j >= mtot) return;

    float qx = 0.f, qy = 0.f, qz = 0.f;
    float negc = -1.0e6f;                       // padded rows never match
    if (j < M) {
        qx = pad[3 * j]; qy = pad[3 * j + 1]; qz = pad[3 * j + 2];
        negc = 0.125f - 0.5f * (qx * qx + qy * qy + qz * qz);   // (r^2 - |q|^2)/2
    }
    const unsigned short xh = f2bf(qx), yh = f2bf(qy), zh = f2bf(qz);
    const unsigned short xl = f2bf(qx - bf2f(xh));
    const unsigned short yl = f2bf(qy - bf2f(yh));
    const unsigned short zl = f2bf(qz - bf2f(zh));
    const unsigned short ch = f2bf(negc);
    const unsigned short cl = f2bf(negc - bf2f(ch));

    uint4 p0, p1;
    p0.x = (unsigned)xh | ((unsigned)yh << 16);   // k0,k1
    p0.y = (unsigned)zh | ((unsigned)xl << 16);   // k2,k3
    p0.z = (unsigned)yl | ((unsigned)zl << 16);   // k4,k5
    p0.w = (unsigned)xh | ((unsigned)yh << 16);   // k6,k7
    p1.x = (unsigned)zh | ((unsigned)xl << 16);   // k8,k9
    p1.y = (unsigned)yl | ((unsigned)zl << 16);   // k10,k11
    p1.z = (unsigned)ch | ((unsigned)cl << 16);   // k12,k13
    p1.w = 0;                                     // k14,k15
    ws[j]        = p0;                            // plane0
    ws[mtot + j] = p1;                            // plane1
}

__device__ __forceinline__ void make_bfrag(const float* __restrict__ pc,
                                           int i, int N, int half,
                                           bf16x8& B, float& ha)
{
    float px = 0.f, py = 0.f, pz = 0.f;
    ha = 3.0e38f;                                // i-pad: s >= 3e38 never true
    if (i < N) {
        px = pc[3 * i]; py = pc[3 * i + 1]; pz = pc[3 * i + 2];
        ha = 0.5f * (px * px + py * py + pz * pz);   // |p|^2/2, fp32
    }
    const short xh = (short)f2bf(px), yh = (short)f2bf(py), zh = (short)f2bf(pz);
    const short xl = (short)f2bf(px - bf2f((unsigned short)xh));
    const short yl = (short)f2bf(py - bf2f((unsigned short)yh));
    const short zl = (short)f2bf(pz - bf2f((unsigned short)zh));
    const short ONE = (short)0x3F80;
    const bf16x8 B0 = {xh, yh, zh, xh, yh, zh, xl, yl};   // k0-7
    const bf16x8 B1 = {zl, xl, yl, zl, ONE, ONE, 0, 0};   // k8-15
    B = half ? B1 : B0;
}

// grid (313 x JS), 256 thr. 64-wide i-tile; STREAMS wave-streams stride j-tiles.
// Per j-tile: 1 dwordx4 A-load (L2-hit) -> 2 MFMAs (C=0, R3/R6-proven numerics),
// results PINNED to ArchVGPRs (kills 32 v_accvgpr_read per visit), then
// interleaved cmp+addc count. Branchless depth-1 prefetch into JTPAD tiles.
__global__ __launch_bounds__(256, 2) void dens_mfma_kernel(
    const float* __restrict__ pc,     // [N,3] pointcloud
    const char*  __restrict__ wsA,    // packed A planes (jt+JTPAD tiles)
    int* __restrict__ out,            // [N] counts (pre-zeroed)
    int N, int jt, int p1off)
{
    const int lane = threadIdx.x & 63;
    const int w    = threadIdx.x >> 6;   // wave 0..3
    const int n    = lane & 31;          // output col within 32-tile = i
    const int half = lane >> 5;          // k-chunk 0/1

    const int ibase = blockIdx.x * 64;
    bf16x8 B0, B1; float ha0, ha1;
    make_bfrag(pc, ibase + n,      N, half, B0, ha0);
    make_bfrag(pc, ibase + 32 + n, N, half, B1, ha1);

    const int stream = blockIdx.y * 4 + w;          // 0..STREAMS-1
    const char* aptr = wsA + (half ? p1off : 0) + n * 16 + (size_t)stream * 512;

    const f32x16 Z = {0.f};                         // zero accumulator
    int c0 = 0, c1 = 0;

    bf16x8 A = *(const bf16x8*)aptr;                // tile `stream`

    #pragma unroll 2
    for (int t = stream; t < jt; t += STREAMS) {
        const bf16x8 An = *(const bf16x8*)(aptr + STREAMS * 512);  // pad-safe
        f32x16 s0 = __builtin_amdgcn_mfma_f32_32x32x16_bf16(A, B0, Z, 0, 0, 0);
        f32x16 s1 = __builtin_amdgcn_mfma_f32_32x32x16_bf16(A, B1, Z, 0, 0, 0);
        // Pin MFMA destinations to ArchVGPRs (gfx950 unified file): the
        // allocator then writes D directly to VGPRs — no v_accvgpr_read
        // round-trip in the consumer loop. Zero instructions emitted.
        asm("" : "+v"(s0));
        asm("" : "+v"(s1));
        #pragma unroll
        for (int r = 0; r < 16; ++r) {
            c0 += (s0[r] >= ha0);      // independent carry chains, interleaved
            c1 += (s1[r] >= ha1);
        }
        A = An;
        aptr += STREAMS * 512;
    }

    // col n lives in lanes n and n+32 (complementary row halves)
    int g0 = c0 + __shfl_xor(c0, 32);
    int g1 = c1 + __shfl_xor(c1, 32);

    __shared__ int red[4][64];
    if (lane < 32) { red[w][n] = g0; red[w][n + 32] = g1; }
    __syncthreads();
    if (threadIdx.x < 64) {
        const int ii = ibase + threadIdx.x;
        if (ii < N) {
            const int s = red[0][threadIdx.x] + red[1][threadIdx.x] +
                          red[2][threadIdx.x] + red[3][threadIdx.x];
            atomicAdd(&out[ii], s);
        }
    }
}

extern "C" void kernel_launch(void* const* d_in, const int* in_sizes, int n_in,
                              void* d_out, int out_size, void* d_ws, size_t ws_size,
                              hipStream_t stream) {
    const float* pc  = (const float*)d_in[0];   // [N,3] pointcloud
    const float* pad = (const float*)d_in[1];   // [M,3] pointcloud_padding
    int* out = (int*)d_out;

    const int N = in_sizes[0] / 3;              // 20000
    const int M = in_sizes[1] / 3;              // 25000
    const int jt   = (M + 31) / 32;             // 782 j-tiles
    const int jtp  = jt + JTPAD;                // + pad tiles for prefetch
    const int mtot = jtp * 32;                  // packed rows (~833 KB in ws)

    dens_pack_kernel<<<(mtot + 255) / 256, 256, 0, stream>>>(
        pad, (uint4*)d_ws, out, M, mtot, N);

    dim3 grid((N + 63) / 64, JS);               // 313 x 8
    dens_mfma_kernel<<<grid, 256, 0, stream>>>(
        pc, (const char*)d_ws, out, N, jt, mtot * 16);
}